// Round 1
// baseline (4083.250 us; speedup 1.0000x reference)
//
#include <hip/hip_runtime.h>

// =====================================================================
// DecoderLayer: selfMHA -> LN -> crossMHA -> LN -> 32xLSTM(pipelined)
//               -> pointwise conv -> LN
// Round 1: fp32 everywhere, correctness-first.
// =====================================================================

#define EPS_LN 1e-5f

// ---------------- fp32 tiled GEMM: C[M,512] = A[M,512]@B[512,512]+bias ----
__global__ __launch_bounds__(256)
void gemm512(const float* __restrict__ A, const float* __restrict__ B,
             const float* __restrict__ bias, float* __restrict__ C, int M) {
  __shared__ float As[16][68];   // [kk][m], pad 68 -> 2-way-free banks
  __shared__ float Bs[16][68];   // [kk][n]
  const int t  = threadIdx.x;
  const int tx = t & 15, ty = t >> 4;
  const int row0 = blockIdx.y * 64;
  const int col0 = blockIdx.x * 64;
  float acc[4][4] = {};
  for (int k0 = 0; k0 < 512; k0 += 16) {
#pragma unroll
    for (int i = 0; i < 4; i++) {
      int idx = t + i * 256;              // 0..1023
      int m  = idx >> 4, kk = idx & 15;
      As[kk][m] = A[(row0 + m) * 512 + k0 + kk];
      int kb = idx >> 6, n = idx & 63;
      Bs[kb][n] = B[(k0 + kb) * 512 + col0 + n];
    }
    __syncthreads();
#pragma unroll
    for (int kk = 0; kk < 16; kk++) {
      float4 a4 = *(const float4*)&As[kk][ty * 4];
      float4 b4 = *(const float4*)&Bs[kk][tx * 4];
      float av[4] = {a4.x, a4.y, a4.z, a4.w};
      float bv[4] = {b4.x, b4.y, b4.z, b4.w};
#pragma unroll
      for (int i = 0; i < 4; i++)
#pragma unroll
        for (int j = 0; j < 4; j++) acc[i][j] += av[i] * bv[j];
    }
    __syncthreads();
  }
  float4 bias4 = *(const float4*)&bias[col0 + tx * 4];
#pragma unroll
  for (int i = 0; i < 4; i++) {
    int gr = row0 + ty * 4 + i;
    if (gr < M) {
      float4 o = make_float4(acc[i][0] + bias4.x, acc[i][1] + bias4.y,
                             acc[i][2] + bias4.z, acc[i][3] + bias4.w);
      *(float4*)&C[gr * 512 + col0 + tx * 4] = o;
    }
  }
}

// ---------------- attention: scores then softmax+PV, per (b,h) -----------
template <int S>
__global__ __launch_bounds__(256)
void attn_scores(const float* __restrict__ Q, const float* __restrict__ K,
                 float* __restrict__ P) {
  __shared__ float Qs[25][64];
  __shared__ float Ks[S][65];           // pad 65: stride-65 reads spread banks
  const int h = blockIdx.x, b = blockIdx.y, t = threadIdx.x;
  for (int idx = t; idx < 25 * 64; idx += 256) {
    int l = idx >> 6, e = idx & 63;
    Qs[l][e] = Q[(b * 25 + l) * 512 + h * 64 + e];
  }
  for (int idx = t; idx < S * 64; idx += 256) {
    int s = idx >> 6, e = idx & 63;
    Ks[s][e] = K[(b * S + s) * 512 + h * 64 + e];
  }
  __syncthreads();
  float* Pb = P + (size_t)(b * 8 + h) * 25 * S;
  for (int idx = t; idx < 25 * S; idx += 256) {
    int l = idx / S, s = idx % S;
    float acc = 0.f;
#pragma unroll
    for (int e = 0; e < 64; e++) acc += Qs[l][e] * Ks[s][e];
    Pb[idx] = acc * 0.125f;             // 1/sqrt(64)
  }
}

template <int S>
__global__ __launch_bounds__(256)
void attn_out(const float* __restrict__ P, const float* __restrict__ V,
              float* __restrict__ O) {
  __shared__ float Ps[25][S];
  __shared__ float Vs[S][64];
  const int h = blockIdx.x, b = blockIdx.y, t = threadIdx.x;
  const float* Pb = P + (size_t)(b * 8 + h) * 25 * S;
  for (int idx = t; idx < 25 * S; idx += 256) Ps[idx / S][idx % S] = Pb[idx];
  for (int idx = t; idx < S * 64; idx += 256) {
    int s = idx >> 6, e = idx & 63;
    Vs[s][e] = V[(b * S + s) * 512 + h * 64 + e];
  }
  __syncthreads();
  if (t < 25) {                         // softmax over S per query row
    float mx = -1e30f;
    for (int s = 0; s < S; s++) mx = fmaxf(mx, Ps[t][s]);
    float sum = 0.f;
    for (int s = 0; s < S; s++) { float p = __expf(Ps[t][s] - mx); Ps[t][s] = p; sum += p; }
    float r = 1.f / sum;
    for (int s = 0; s < S; s++) Ps[t][s] *= r;
  }
  __syncthreads();
  for (int idx = t; idx < 25 * 64; idx += 256) {
    int l = idx >> 6, e = idx & 63;
    float acc = 0.f;
    for (int s = 0; s < S; s++) acc += Ps[l][s] * Vs[s][e];
    O[(b * 25 + l) * 512 + h * 64 + e] = acc;
  }
}

// ---------------- fused residual-add + LayerNorm (rows of 512) -----------
__global__ __launch_bounds__(128)
void add_ln(const float* __restrict__ a, const float* __restrict__ b,
            const float* __restrict__ gw, const float* __restrict__ bw,
            float* __restrict__ out) {
  const int row = blockIdx.x, t = threadIdx.x;       // 128 thr * float4 = 512
  float4 va = ((const float4*)(a + (size_t)row * 512))[t];
  float4 vb = ((const float4*)(b + (size_t)row * 512))[t];
  float4 v = make_float4(va.x + vb.x, va.y + vb.y, va.z + vb.z, va.w + vb.w);
  float s = v.x + v.y + v.z + v.w;
  float q = v.x * v.x + v.y * v.y + v.z * v.z + v.w * v.w;
#pragma unroll
  for (int off = 32; off > 0; off >>= 1) {
    s += __shfl_down(s, off);
    q += __shfl_down(q, off);
  }
  __shared__ float red[4];
  if ((t & 63) == 0) { red[(t >> 6) * 2] = s; red[(t >> 6) * 2 + 1] = q; }
  __syncthreads();
  float S_ = red[0] + red[2], Q_ = red[1] + red[3];
  float mean = S_ * (1.f / 512.f);
  float var  = Q_ * (1.f / 512.f) - mean * mean;    // biased, as torch LN
  float inv  = rsqrtf(var + EPS_LN);
  float4 g4 = ((const float4*)gw)[t];
  float4 b4 = ((const float4*)bw)[t];
  float4 o;
  o.x = (v.x - mean) * inv * g4.x + b4.x;
  o.y = (v.y - mean) * inv * g4.y + b4.y;
  o.z = (v.z - mean) * inv * g4.z + b4.z;
  o.w = (v.w - mean) * inv * g4.w + b4.w;
  ((float4*)(out + (size_t)row * 512))[t] = o;
}

// ---------------- transposes --------------------------------------------
__global__ void transpose_ld(const float* __restrict__ in, float* __restrict__ outp) {
  // out[b][d=512][l=25] = in[b][l][d]
  const int b = blockIdx.x, t = threadIdx.x;
  for (int idx = t; idx < 512 * 25; idx += 256) {
    int d = idx / 25, l2 = idx % 25;
    outp[((size_t)b * 512 + d) * 25 + l2] = in[((size_t)b * 25 + l2) * 512 + d];
  }
}
__global__ void transpose_dl(const float* __restrict__ in, float* __restrict__ outp) {
  // out[b][l=25][c=512] = in[b][c][l]
  const int b = blockIdx.x, t = threadIdx.x;
  for (int idx = t; idx < 25 * 512; idx += 256) {
    int l2 = idx / 512, c = idx % 512;
    outp[((size_t)b * 25 + l2) * 512 + c] = in[((size_t)b * 512 + c) * 25 + l2];
  }
}
__global__ void transpose_sq(const float* __restrict__ in, float* __restrict__ outp) {
  const int c = blockIdx.x, t = threadIdx.x;
  for (int o = t; o < 512; o += 256) outp[(size_t)c * 512 + o] = in[(size_t)o * 512 + c];
}

// ---------------- pipelined 32-layer LSTM --------------------------------
// grid = 32 layers x 8 batch-groups (blockIdx = l*8+g => chain stays on one
// XCD under blockIdx%8 round-robin). 256 blocks = 1/CU -> all co-resident.
// h-streams flow layer l -> l+1 through a 64-slot ring in global memory;
// progress via agent-scope acquire/release counters (cross-XCD safe).
#define NLAY 32
#define NT   512
#define NB   128
#define NGRP 8
#define BGRP 16          // batches per group
#define CHT  8           // timesteps per chunk
#define NCHK 64          // chunks (512/8)
#define RCHK 8           // ring depth in chunks
#define RT   64          // ring slots in timesteps

__device__ __forceinline__ int ld_acq(int* p) {
  return __hip_atomic_load(p, __ATOMIC_ACQUIRE, __HIP_MEMORY_SCOPE_AGENT);
}
__device__ __forceinline__ void st_rel(int* p, int v) {
  __hip_atomic_store(p, v, __ATOMIC_RELEASE, __HIP_MEMORY_SCOPE_AGENT);
}

__global__ __launch_bounds__(256)
void lstm_pipeline(const float* __restrict__ y0, float* __restrict__ yout,
                   float* __restrict__ ring, int* __restrict__ prod,
                   int* __restrict__ cons,
                   const float* __restrict__ Wih, const float* __restrict__ Whh,
                   const float* __restrict__ bih, const float* __restrict__ bhh) {
  const int l = blockIdx.x >> 3;
  const int g = blockIdx.x & 7;
  const int t = threadIdx.x;

  __shared__ float xbuf[CHT][BGRP][28];  // k padded 25->28 (16B-aligned rows)
  __shared__ float hbuf[BGRP][28];
  __shared__ float cbuf[BGRP][25];
  __shared__ float gates[100][17];       // [gate j][bi], stride 17 (bank-safe)

  // ---- load this layer's weights into registers (thread = gate row j) ----
  float4 wih4[7], whh4[7];
  float biasr = 0.f;
  {
    float* wsh = &xbuf[0][0][0];         // 3584 floats staging (need 2800)
    for (int idx = t; idx < 100 * 28; idx += 256) {
      int j = idx / 28, k = idx % 28;
      wsh[idx] = (k < 25) ? Wih[((size_t)l * 100 + j) * 25 + k] : 0.f;
    }
    __syncthreads();
    if (t < 200) {
      int j = t % 100;
#pragma unroll
      for (int kk = 0; kk < 7; kk++) wih4[kk] = *(const float4*)&wsh[j * 28 + kk * 4];
    }
    __syncthreads();
    for (int idx = t; idx < 100 * 28; idx += 256) {
      int j = idx / 28, k = idx % 28;
      wsh[idx] = (k < 25) ? Whh[((size_t)l * 100 + j) * 25 + k] : 0.f;
    }
    __syncthreads();
    if (t < 200) {
      int j = t % 100;
#pragma unroll
      for (int kk = 0; kk < 7; kk++) whh4[kk] = *(const float4*)&wsh[j * 28 + kk * 4];
      biasr = bih[l * 100 + j] + bhh[l * 100 + j];
    }
    __syncthreads();
  }
  // zero LDS state (pads must be 0: pad-weights are 0 but 0*NaN poisons acc)
  for (int idx = t; idx < CHT * BGRP * 28; idx += 256) (&xbuf[0][0][0])[idx] = 0.f;
  for (int idx = t; idx < BGRP * 28; idx += 256) (&hbuf[0][0])[idx] = 0.f;
  for (int idx = t; idx < BGRP * 25; idx += 256) (&cbuf[0][0])[idx] = 0.f;
  __syncthreads();

  const int jj = t % 100;
  const int half = t / 100;              // t<200 active in gate phase

  for (int n = 0; n < NCHK; n++) {
    if (t == 0) {
      if (l > 0) {                       // wait for input chunk n
        int* p = &prod[(l - 1) * NGRP + g];
        while (ld_acq(p) < n + 1) __builtin_amdgcn_s_sleep(8);
      }
      if (l < NLAY - 1 && n >= RCHK) {   // wait for ring slots to free
        int* p = &cons[(l + 1) * NGRP + g];
        while (ld_acq(p) < n - RCHK + 1) __builtin_amdgcn_s_sleep(8);
      }
    }
    __syncthreads();
    // stage chunk input into LDS
    for (int idx = t; idx < CHT * BGRP * 25; idx += 256) {
      int tc = idx / (BGRP * 25);
      int r  = idx % (BGRP * 25);
      int bi = r / 25, k = r % 25;
      int tg = n * CHT + tc;
      int b  = g * BGRP + bi;
      float v = (l == 0)
          ? y0[((size_t)b * NT + tg) * 25 + k]
          : ring[(((size_t)(l - 1) * NB + b) * RT + (tg & (RT - 1))) * 25 + k];
      xbuf[tc][bi][k] = v;
    }
    __syncthreads();
    if (t == 0 && l > 0) st_rel(&cons[l * NGRP + g], n + 1);

    for (int tc = 0; tc < CHT; tc++) {
      if (t < 200) {                     // gates = x@Wih^T + h@Whh^T + bias
#pragma unroll
        for (int b8 = 0; b8 < 8; b8++) {
          int bi = half * 8 + b8;
          const float4* xp = (const float4*)&xbuf[tc][bi][0];
          const float4* hp = (const float4*)&hbuf[bi][0];
          float sx = 0.f, sy = 0.f, sz = 0.f, sw = 0.f;
#pragma unroll
          for (int kk = 0; kk < 7; kk++) {
            float4 xv = xp[kk], hv = hp[kk];
            sx += wih4[kk].x * xv.x + whh4[kk].x * hv.x;
            sy += wih4[kk].y * xv.y + whh4[kk].y * hv.y;
            sz += wih4[kk].z * xv.z + whh4[kk].z * hv.z;
            sw += wih4[kk].w * xv.w + whh4[kk].w * hv.w;
          }
          gates[jj][bi] = sx + sy + sz + sw + biasr;
        }
      }
      __syncthreads();
      for (int idx = t; idx < BGRP * 25; idx += 256) {
        int bi = idx / 25, u = idx % 25;
        float gi = gates[u][bi];
        float gf = gates[25 + u][bi];
        float gg = gates[50 + u][bi];
        float go = gates[75 + u][bi];
        float si = 1.f / (1.f + __expf(-gi));
        float sf = 1.f / (1.f + __expf(-gf));
        float so = 1.f / (1.f + __expf(-go));
        float c  = sf * cbuf[bi][u] + si * tanhf(gg);
        float h  = so * tanhf(c);
        cbuf[bi][u] = c;
        hbuf[bi][u] = h;
        int tg2 = n * CHT + tc;
        int b   = g * BGRP + bi;
        if (l == NLAY - 1)
          yout[((size_t)b * NT + tg2) * 25 + u] = h;
        else
          ring[(((size_t)l * NB + b) * RT + (tg2 & (RT - 1))) * 25 + u] = h;
      }
      __syncthreads();
    }
    if (t == 0 && l < NLAY - 1) st_rel(&prod[l * NGRP + g], n + 1);
  }
}

// =====================================================================
extern "C" void kernel_launch(void* const* d_in, const int* in_sizes, int n_in,
                              void* d_out, int out_size, void* d_ws, size_t ws_size,
                              hipStream_t stream) {
  const float* x     = (const float*)d_in[0];
  const float* cross = (const float*)d_in[1];
  const float* Wq_s = (const float*)d_in[2];  const float* bq_s = (const float*)d_in[3];
  const float* Wk_s = (const float*)d_in[4];  const float* bk_s = (const float*)d_in[5];
  const float* Wv_s = (const float*)d_in[6];  const float* bv_s = (const float*)d_in[7];
  const float* Wo_s = (const float*)d_in[8];  const float* bo_s = (const float*)d_in[9];
  const float* Wq_c = (const float*)d_in[10]; const float* bq_c = (const float*)d_in[11];
  const float* Wk_c = (const float*)d_in[12]; const float* bk_c = (const float*)d_in[13];
  const float* Wv_c = (const float*)d_in[14]; const float* bv_c = (const float*)d_in[15];
  const float* Wo_c = (const float*)d_in[16]; const float* bo_c = (const float*)d_in[17];
  const float* g1 = (const float*)d_in[18]; const float* b1 = (const float*)d_in[19];
  const float* g2 = (const float*)d_in[20]; const float* b2 = (const float*)d_in[21];
  const float* g3 = (const float*)d_in[22]; const float* b3 = (const float*)d_in[23];
  const float* Wih = (const float*)d_in[24];
  const float* Whh = (const float*)d_in[25];
  const float* bih = (const float*)d_in[26];
  const float* bhh = (const float*)d_in[27];
  const float* Wc  = (const float*)d_in[28]; const float* bc = (const float*)d_in[29];
  float* out = (float*)d_out;
  float* ws  = (float*)d_ws;

  // ---- workspace layout (floats), liveness-based reuse; peak ~76 MiB ----
  constexpr size_t A = 1638400;    // 3200*512
  constexpr size_t Cc = 6291456;   // 12288*512
  float* x1    = ws;               // live: LN1 .. LN2
  float* Qc    = ws + A;
  float* Kc    = ws + 2 * A;       // cross K/V region 2A..2A+2C
  float* Vc    = ws + 2 * A + Cc;
  float* attnc = ws + 2 * A + 2 * Cc;
  float* Pc    = attnc + A;                     // 2,457,600 floats
  int*   ctr   = (int*)(Pc + 2457600);          // 512 ints (prod|cons)
  // self-attention phase aliases (inside later K/V region; disjoint in time)
  float* Qs    = ws + 2 * A;
  float* Ks    = ws + 3 * A;
  float* Vs    = ws + 4 * A;
  float* attns = ws + 5 * A;
  float* tmp   = ws + 6 * A;
  float* Ps    = ws + 7 * A;                    // 640,000 floats
  // post-cross aliases
  float* tmp2  = ws + 2 * A;
  float* x2    = ws + 3 * A;       // live until final LN
  float* y0b   = ws + 4 * A;
  float* youtb = ws + 5 * A;
  float* ringb = ws + 6 * A;       // 6,553,600 floats (6A..10A), LSTM only
  float* ytb   = ws + 2 * A;       // after LSTM
  float* WcT   = ws + 6 * A;       // after LSTM (ring dead)
  float* fy    = ws + 7 * A;

  hipMemsetAsync(ctr, 0, 512 * sizeof(int), stream);   // counters must be 0

  dim3 blk(256);
  // ---- self attention ----
  gemm512<<<dim3(8, 50), blk, 0, stream>>>(x, Wq_s, bq_s, Qs, 3200);
  gemm512<<<dim3(8, 50), blk, 0, stream>>>(x, Wk_s, bk_s, Ks, 3200);
  gemm512<<<dim3(8, 50), blk, 0, stream>>>(x, Wv_s, bv_s, Vs, 3200);
  attn_scores<25><<<dim3(8, 128), blk, 0, stream>>>(Qs, Ks, Ps);
  attn_out<25><<<dim3(8, 128), blk, 0, stream>>>(Ps, Vs, attns);
  gemm512<<<dim3(8, 50), blk, 0, stream>>>(attns, Wo_s, bo_s, tmp, 3200);
  add_ln<<<3200, 128, 0, stream>>>(x, tmp, g1, b1, x1);
  // ---- cross attention ----
  gemm512<<<dim3(8, 50), blk, 0, stream>>>(x1, Wq_c, bq_c, Qc, 3200);
  gemm512<<<dim3(8, 192), blk, 0, stream>>>(cross, Wk_c, bk_c, Kc, 12288);
  gemm512<<<dim3(8, 192), blk, 0, stream>>>(cross, Wv_c, bv_c, Vc, 12288);
  attn_scores<96><<<dim3(8, 128), blk, 0, stream>>>(Qc, Kc, Pc);
  attn_out<96><<<dim3(8, 128), blk, 0, stream>>>(Pc, Vc, attnc);
  gemm512<<<dim3(8, 50), blk, 0, stream>>>(attnc, Wo_c, bo_c, tmp2, 3200);
  add_ln<<<3200, 128, 0, stream>>>(x1, tmp2, g2, b2, x2);
  // ---- LSTM over feature axis ----
  transpose_ld<<<128, 256, 0, stream>>>(x2, y0b);
  lstm_pipeline<<<256, 256, 0, stream>>>(y0b, youtb, ringb, ctr, ctr + 256,
                                         Wih, Whh, bih, bhh);
  // ---- pointwise conv over channels + final LN ----
  transpose_dl<<<128, 256, 0, stream>>>(youtb, ytb);
  transpose_sq<<<512, 256, 0, stream>>>(Wc, WcT);
  gemm512<<<dim3(8, 50), blk, 0, stream>>>(ytb, WcT, bc, fy, 3200);
  add_ln<<<3200, 128, 0, stream>>>(x2, fy, g3, b3, out);
}